// Round 7
// baseline (721.858 us; speedup 1.0000x reference)
//
#include <hip/hip_runtime.h>
#include <stdint.h>

#define F 16
#define CDIM 320
#define DDIM 4096
#define NSEQ 8192
#define WPB 2
#define THREADS (WPB*64)
#define NT 20
#define KS 10
#define HBUF 6144   // [16][384B] half buffer: 320B data + 64B pad for 8-way swizzle

typedef __attribute__((ext_vector_type(8))) short short8;
typedef __attribute__((ext_vector_type(4))) float f32x4;

__device__ __forceinline__ unsigned short f2bf(float f) {
    union { float f; uint32_t u; } v; v.f = f;
    uint32_t r = v.u + 0x7FFFu + ((v.u >> 16) & 1u);   // RTNE
    return (unsigned short)(r >> 16);
}
__device__ __forceinline__ float bf2f(unsigned short h) {
    union { uint32_t u; float f; } v; v.u = ((uint32_t)h) << 16;
    return v.f;
}
// half-buffer swizzle: [16][384B] rows (20 data chunks + 4 pad chunks of 16B).
// chunk ^ (row&7) <= 23 always fits the 24-chunk row; 384B = 96 dwords == 0
// mod 32 banks, and the 8-chunk XOR span covers all 32 banks -> conflict-free
// b128 column reads.
__device__ __forceinline__ int hswz(int row, int b) {
    return row * 384 + (b ^ ((row & 7) << 4));
}

// One-time: pack Wq/Wk/Wv/Wo (fp32 row-major [320][320]) into bf16 B-fragment
// order. Fragment (m, nt, ks) is a 1KB block: lane (g,lr) holds
// W[nt*16+lr][ks*32+g*8 .. +7]. Byte offset = ((m*NT+nt)*KS+ks)*1024 + lane*16.
__global__ __launch_bounds__(256)
void pack_weights_kernel(const float* __restrict__ Wq, const float* __restrict__ Wk,
                         const float* __restrict__ Wv, const float* __restrict__ Wo,
                         char* __restrict__ pk)
{
    const int t = blockIdx.x * 256 + threadIdx.x;
    if (t >= 4 * NT * KS * 64) return;
    const int lane = t & 63;
    const int rest = t >> 6;
    const int ks = rest % KS;
    const int nt = (rest / KS) % NT;
    const int m  = rest / (KS * NT);
    const float* W = (m == 0) ? Wq : (m == 1) ? Wk : (m == 2) ? Wv : Wo;
    const int g = lane >> 4, lr = lane & 15;
    const float* src = W + (size_t)(nt * 16 + lr) * CDIM + ks * 32 + g * 8;
    const f32x4 a = *(const f32x4*)src;
    const f32x4 b = *(const f32x4*)(src + 4);
    float vals[8] = {a[0], a[1], a[2], a[3], b[0], b[1], b[2], b[3]};
    short8 o;
#pragma unroll
    for (int j = 0; j < 8; ++j) o[j] = (short)f2bf(vals[j]);
    *(short8*)(pk + (size_t)t * 16) = o;
}

// R3-R5 lesson (revised): spills came from register arrays ([h2]-indexed)
// whose static indexing required unrolling a huge region. Here the h2 loop
// is RUNTIME (#pragma unroll 1) and no register array is h2-indexed; the
// only h2-dependent state is an LDS pointer (runtime addressing is fine).
__global__ __launch_bounds__(THREADS, 2)
void temporal_attn_kernel(const float* __restrict__ hs,
                          const char* __restrict__ wpk,
                          const float* __restrict__ bo,
                          float* __restrict__ out)
{
    extern __shared__ __align__(16) char smem[];
    const int tid  = threadIdx.x;
    const int lane = tid & 63;
    const int wave = tid >> 6;
    const int g    = lane >> 4;
    const int lr   = lane & 15;

    const int seq = blockIdx.x * WPB + wave;
    const int bi  = seq >> 12;
    const int di  = seq & (DDIM - 1);

    char* const X0 = smem + wave * (2 * HBUF);   // half0: Q->K->V->attn-out
    char* const X1 = X0 + HBUF;                  // half1: Q->K->V->attn-out
    const char* const wl = wpk + lane * 16;

    // ---- load x rows, add PE, convert to bf16 A-fragments ----
    const float* xrow = hs + ((size_t)(bi * F + lr) * DDIM + di) * CDIM;
    short8 axk[KS];
#pragma unroll
    for (int ks = 0; ks < KS; ++ks) {
        const int k0 = ks * 32 + g * 8;
        const f32x4 a = __builtin_nontemporal_load((const f32x4*)(xrow + k0));
        const f32x4 b = __builtin_nontemporal_load((const f32x4*)(xrow + k0 + 4));
        float xv[8] = {a[0], a[1], a[2], a[3], b[0], b[1], b[2], b[3]};
#pragma unroll
        for (int jj = 0; jj < 4; ++jj) {
            const float c0 = (float)(k0 + 2 * jj);
            const float dv = __expf(c0 * -0.028782313662425575f); // -ln(1e4)/320
            const float ang = (float)lr * dv;                      // pos = frame
            xv[2 * jj]     += __sinf(ang);
            xv[2 * jj + 1] += __cosf(ang);
        }
        short8 t;
#pragma unroll
        for (int j = 0; j < 8; ++j) t[j] = (short)f2bf(xv[j]);
        axk[ks] = t;
    }

    // ---- half-width projection (10 col-tiles), ping-pong pipelined ----
    auto projh = [&](int m, int h2, char* dst) {
        const char* base = wl + (size_t)((m * NT + h2 * 10) * KS) * 1024;
        short8 fa[KS], fb[KS];
#pragma unroll
        for (int ks = 0; ks < KS; ++ks)
            fa[ks] = *(const short8*)(base + (size_t)ks * 1024);
#pragma unroll 1
        for (int np = 0; np < 5; ++np) {
#pragma unroll
            for (int ks = 0; ks < KS; ++ks)
                fb[ks] = *(const short8*)(base + (size_t)((2 * np + 1) * KS + ks) * 1024);
            f32x4 a0 = {0.f, 0.f, 0.f, 0.f};
#pragma unroll
            for (int ks = 0; ks < KS; ++ks)
                a0 = __builtin_amdgcn_mfma_f32_16x16x32_bf16(axk[ks], fa[ks], a0, 0, 0, 0);
            if (np < 4) {
#pragma unroll
                for (int ks = 0; ks < KS; ++ks)
                    fa[ks] = *(const short8*)(base + (size_t)((2 * np + 2) * KS + ks) * 1024);
            }
            f32x4 a1 = {0.f, 0.f, 0.f, 0.f};
#pragma unroll
            for (int ks = 0; ks < KS; ++ks)
                a1 = __builtin_amdgcn_mfma_f32_16x16x32_bf16(axk[ks], fb[ks], a1, 0, 0, 0);
            // local cols 2np*16+lr and (2np+1)*16+lr -> bytes 64np+2lr, +32
#pragma unroll
            for (int r = 0; r < 4; ++r) {
                const int row = g * 4 + r;
                *(short*)(dst + hswz(row, 64 * np + 2 * lr))      = (short)f2bf(a0[r]);
                *(short*)(dst + hswz(row, 64 * np + 32 + 2 * lr)) = (short)f2bf(a1[r]);
            }
        }
    };

    const float scale = 0.15811388300841897f;  // 40^-0.5
    const int cb = g * 80;   // byte base of local head g inside a half row

#pragma unroll 1   // RUNTIME loop: small region, no h2-indexed register arrays
    for (int h2 = 0; h2 < 2; ++h2) {
        char* const X = h2 ? X1 : X0;

        projh(0, h2, X);               // Q half -> X
        short8 qp[5];                  // loop-local, statically indexed
#pragma unroll
        for (int j5 = 0; j5 < 5; ++j5)
            qp[j5] = *(const short8*)(X + hswz(lr, cb + j5 * 16));

        projh(1, h2, X);               // K overwrites Q (qp extracted)

        float s[F];
#pragma unroll
        for (int kk = 0; kk < F; ++kk) s[kk] = 0.f;
#pragma unroll
        for (int j5 = 0; j5 < 5; ++j5) {
            float qf[8];
#pragma unroll
            for (int j = 0; j < 8; ++j) qf[j] = bf2f((unsigned short)qp[j5][j]);
#pragma unroll
            for (int kk = 0; kk < F; ++kk) {
                short8 k8 = *(const short8*)(X + hswz(kk, cb + j5 * 16));
#pragma unroll
                for (int j = 0; j < 8; ++j) s[kk] += qf[j] * bf2f((unsigned short)k8[j]);
            }
        }
        float m = -1e30f;
#pragma unroll
        for (int kk = 0; kk < F; ++kk) {
            s[kk] = (kk <= lr) ? s[kk] * scale : -1e30f;
            m = fmaxf(m, s[kk]);
        }
        float sum = 0.f;
#pragma unroll
        for (int kk = 0; kk < F; ++kk) { s[kk] = __expf(s[kk] - m); sum += s[kk]; }
        const float inv = 1.f / sum;
#pragma unroll
        for (int kk = 0; kk < F; ++kk) s[kk] *= inv;

        projh(2, h2, X);               // V overwrites K (scores in regs)

        // PV chunked; attn-out overwrites V in place. For chunk j5: all 16
        // row-reads of chunk j5 precede the single row-lr write of chunk j5;
        // later chunks j5+1.. are untouched (per-row bijective swizzle).
#pragma unroll
        for (int j5 = 0; j5 < 5; ++j5) {
            float a8[8];
#pragma unroll
            for (int j = 0; j < 8; ++j) a8[j] = 0.f;
#pragma unroll
            for (int kk = 0; kk < F; ++kk) {
                short8 v8 = *(const short8*)(X + hswz(kk, cb + j5 * 16));
#pragma unroll
                for (int j = 0; j < 8; ++j) a8[j] += s[kk] * bf2f((unsigned short)v8[j]);
            }
            short8 t;
#pragma unroll
            for (int j = 0; j < 8; ++j) t[j] = (short)f2bf(a8[j]);
            *(short8*)(X + hswz(lr, cb + j5 * 16)) = t;
        }
    }

    // ---- output projection: out = ao @ Wo.T + bo ----
    // A-frag ks: global dims ks*32+g*8 -> half ks/5 (static), local chunk
    // ks*4+g-20*(ks/5)
    short8 aof[KS];
#pragma unroll
    for (int ks = 0; ks < KS; ++ks) {
        const char* Xh = (ks < 5) ? X0 : X1;
        const int chunk = ks * 4 + g - 20 * (ks / 5);
        aof[ks] = *(const short8*)(Xh + hswz(lr, chunk * 16));
    }

    {
        const char* base = wl + (size_t)(3 * NT) * KS * 1024;
        short8 fa[KS], fb[KS];
#pragma unroll
        for (int ks = 0; ks < KS; ++ks)
            fa[ks] = *(const short8*)(base + (size_t)ks * 1024);
#pragma unroll 1
        for (int np = 0; np < 10; ++np) {
#pragma unroll
            for (int ks = 0; ks < KS; ++ks)
                fb[ks] = *(const short8*)(base + (size_t)((2 * np + 1) * KS + ks) * 1024);
            f32x4 a0 = {0.f, 0.f, 0.f, 0.f};
#pragma unroll
            for (int ks = 0; ks < KS; ++ks)
                a0 = __builtin_amdgcn_mfma_f32_16x16x32_bf16(aof[ks], fa[ks], a0, 0, 0, 0);
            if (np < 9) {
#pragma unroll
                for (int ks = 0; ks < KS; ++ks)
                    fa[ks] = *(const short8*)(base + (size_t)((2 * np + 2) * KS + ks) * 1024);
            }
            f32x4 a1 = {0.f, 0.f, 0.f, 0.f};
#pragma unroll
            for (int ks = 0; ks < KS; ++ks)
                a1 = __builtin_amdgcn_mfma_f32_16x16x32_bf16(aof[ks], fb[ks], a1, 0, 0, 0);

            const int c0 = 2 * np * 16 + lr;
            const int c1 = c0 + 16;
            const float bias0 = bo[c0];
            const float bias1 = bo[c1];
            // paired stores cover one full 128B line per output row
#pragma unroll
            for (int r = 0; r < 4; ++r) {
                float* rowp = out + ((size_t)(bi * F + g * 4 + r) * DDIM + di) * CDIM;
                rowp[c0] = a0[r] + bias0;
                rowp[c1] = a1[r] + bias1;
            }
        }
    }
}

extern "C" void kernel_launch(void* const* d_in, const int* in_sizes, int n_in,
                              void* d_out, int out_size, void* d_ws, size_t ws_size,
                              hipStream_t stream) {
    const float* hs = (const float*)d_in[0];
    const float* Wq = (const float*)d_in[1];
    const float* Wk = (const float*)d_in[2];
    const float* Wv = (const float*)d_in[3];
    const float* Wo = (const float*)d_in[4];
    const float* bo = (const float*)d_in[5];
    float* out = (float*)d_out;
    char* wpk = (char*)d_ws;   // 4*200*1024 = 819200 B of packed bf16 weights

    pack_weights_kernel<<<dim3((4 * NT * KS * 64 + 255) / 256), dim3(256), 0, stream>>>(
        Wq, Wk, Wv, Wo, wpk);

    const int lds = WPB * 2 * HBUF;   // 24576 B -> 6 blocks/CU (12 waves/CU)
    (void)hipFuncSetAttribute((const void*)temporal_attn_kernel,
                              hipFuncAttributeMaxDynamicSharedMemorySize, lds);
    temporal_attn_kernel<<<dim3(NSEQ / WPB), dim3(THREADS), lds, stream>>>(
        hs, wpk, bo, out);
}

// Round 8
// 574.431 us; speedup vs baseline: 1.2566x; 1.2566x over previous
//
#include <hip/hip_runtime.h>
#include <stdint.h>

#define F 16
#define CDIM 320
#define DDIM 4096
#define NSEQ 8192
#define WPB 4
#define THREADS (WPB*64)
#define NT 20
#define KS 10
#define HBUF 5120   // [16][320B] half buffer, no pad; &3 XOR swizzle stays in-bounds

typedef __attribute__((ext_vector_type(8))) short short8;
typedef __attribute__((ext_vector_type(4))) float f32x4;

__device__ __forceinline__ unsigned short f2bf(float f) {
    union { float f; uint32_t u; } v; v.f = f;
    uint32_t r = v.u + 0x7FFFu + ((v.u >> 16) & 1u);   // RTNE
    return (unsigned short)(r >> 16);
}
__device__ __forceinline__ float bf2f(unsigned short h) {
    union { uint32_t u; float f; } v; v.u = ((uint32_t)h) << 16;
    return v.f;
}
// half-buffer swizzle: [16][320B] rows = 20 chunks of 16B. chunk ^ (row&3)
// permutes within complete 4-chunk groups (20 = 5 groups) -> always in-bounds,
// bijective per row.
__device__ __forceinline__ int hswz(int row, int b) {
    return row * 320 + (b ^ ((row & 3) << 4));
}

// One-time: pack Wq/Wk/Wv/Wo (fp32 row-major [320][320]) into bf16 B-fragment
// order. Fragment (m, nt, ks) is a 1KB block: lane (g,lr) holds
// W[nt*16+lr][ks*32+g*8 .. +7]. Byte offset = ((m*NT+nt)*KS+ks)*1024 + lane*16.
__global__ __launch_bounds__(256)
void pack_weights_kernel(const float* __restrict__ Wq, const float* __restrict__ Wk,
                         const float* __restrict__ Wv, const float* __restrict__ Wo,
                         char* __restrict__ pk)
{
    const int t = blockIdx.x * 256 + threadIdx.x;
    if (t >= 4 * NT * KS * 64) return;
    const int lane = t & 63;
    const int rest = t >> 6;
    const int ks = rest % KS;
    const int nt = (rest / KS) % NT;
    const int m  = rest / (KS * NT);
    const float* W = (m == 0) ? Wq : (m == 1) ? Wk : (m == 2) ? Wv : Wo;
    const int g = lane >> 4, lr = lane & 15;
    const float* src = W + (size_t)(nt * 16 + lr) * CDIM + ks * 32 + g * 8;
    const f32x4 a = *(const f32x4*)src;
    const f32x4 b = *(const f32x4*)(src + 4);
    float vals[8] = {a[0], a[1], a[2], a[3], b[0], b[1], b[2], b[3]};
    short8 o;
#pragma unroll
    for (int j = 0; j < 8; ++j) o[j] = (short)f2bf(vals[j]);
    *(short8*)(pk + (size_t)t * 16) = o;
}

// Session lessons baked in:
//  - ONLY (256,2) launch bounds have ever been spill-free (R2:88, R6:104 VGPR).
//    Any tighter cap (R3/R4/R5/R7) -> allocator spills in unrolled loops ->
//    GB-scale FETCH/WRITE. Do not tighten.
//  - Runtime h2 loop; no register array indexed by h2 (rule #20).
//  - Single-buffer half-pass: X reused Q->K->V->attn-out in place (R7-proven
//    dataflow), 10 KB/wave -> 40 KB/block -> 4 blocks/CU.
__global__ __launch_bounds__(THREADS, 2)
void temporal_attn_kernel(const float* __restrict__ hs,
                          const char* __restrict__ wpk,
                          const float* __restrict__ bo,
                          float* __restrict__ out)
{
    extern __shared__ __align__(16) char smem[];
    const int tid  = threadIdx.x;
    const int lane = tid & 63;
    const int wave = tid >> 6;
    const int g    = lane >> 4;
    const int lr   = lane & 15;

    const int seq = blockIdx.x * WPB + wave;
    const int bi  = seq >> 12;
    const int di  = seq & (DDIM - 1);

    char* const X0 = smem + wave * (2 * HBUF);   // half0: Q->K->V->attn-out
    char* const X1 = X0 + HBUF;                  // half1: Q->K->V->attn-out
    const char* const wl = wpk + lane * 16;

    // ---- load x rows, add PE, convert to bf16 A-fragments ----
    const float* xrow = hs + ((size_t)(bi * F + lr) * DDIM + di) * CDIM;
    short8 axk[KS];
#pragma unroll
    for (int ks = 0; ks < KS; ++ks) {
        const int k0 = ks * 32 + g * 8;
        const f32x4 a = __builtin_nontemporal_load((const f32x4*)(xrow + k0));
        const f32x4 b = __builtin_nontemporal_load((const f32x4*)(xrow + k0 + 4));
        float xv[8] = {a[0], a[1], a[2], a[3], b[0], b[1], b[2], b[3]};
#pragma unroll
        for (int jj = 0; jj < 4; ++jj) {
            const float c0 = (float)(k0 + 2 * jj);
            const float dv = __expf(c0 * -0.028782313662425575f); // -ln(1e4)/320
            const float ang = (float)lr * dv;                      // pos = frame
            xv[2 * jj]     += __sinf(ang);
            xv[2 * jj + 1] += __cosf(ang);
        }
        short8 t;
#pragma unroll
        for (int j = 0; j < 8; ++j) t[j] = (short)f2bf(xv[j]);
        axk[ks] = t;
    }

    // ---- half-width projection (10 col-tiles), ping-pong pipelined ----
    auto projh = [&](int m, int h2, char* dst) {
        const char* base = wl + (size_t)((m * NT + h2 * 10) * KS) * 1024;
        short8 fa[KS], fb[KS];
#pragma unroll
        for (int ks = 0; ks < KS; ++ks)
            fa[ks] = *(const short8*)(base + (size_t)ks * 1024);
#pragma unroll 1
        for (int np = 0; np < 5; ++np) {
#pragma unroll
            for (int ks = 0; ks < KS; ++ks)
                fb[ks] = *(const short8*)(base + (size_t)((2 * np + 1) * KS + ks) * 1024);
            f32x4 a0 = {0.f, 0.f, 0.f, 0.f};
#pragma unroll
            for (int ks = 0; ks < KS; ++ks)
                a0 = __builtin_amdgcn_mfma_f32_16x16x32_bf16(axk[ks], fa[ks], a0, 0, 0, 0);
            if (np < 4) {
#pragma unroll
                for (int ks = 0; ks < KS; ++ks)
                    fa[ks] = *(const short8*)(base + (size_t)((2 * np + 2) * KS + ks) * 1024);
            }
            f32x4 a1 = {0.f, 0.f, 0.f, 0.f};
#pragma unroll
            for (int ks = 0; ks < KS; ++ks)
                a1 = __builtin_amdgcn_mfma_f32_16x16x32_bf16(axk[ks], fb[ks], a1, 0, 0, 0);
            // local cols 2np*16+lr and (2np+1)*16+lr -> bytes 64np+2lr, +32
#pragma unroll
            for (int r = 0; r < 4; ++r) {
                const int row = g * 4 + r;
                *(short*)(dst + hswz(row, 64 * np + 2 * lr))      = (short)f2bf(a0[r]);
                *(short*)(dst + hswz(row, 64 * np + 32 + 2 * lr)) = (short)f2bf(a1[r]);
            }
        }
    };

    const float scale = 0.15811388300841897f;  // 40^-0.5
    const int cb = g * 80;   // byte base of local head g inside a half row

#pragma unroll 1   // RUNTIME loop: no h2-indexed register arrays (rule #20)
    for (int h2 = 0; h2 < 2; ++h2) {
        char* const X = h2 ? X1 : X0;

        projh(0, h2, X);               // Q half -> X
        short8 qp[5];                  // loop-local, statically indexed
#pragma unroll
        for (int j5 = 0; j5 < 5; ++j5)
            qp[j5] = *(const short8*)(X + hswz(lr, cb + j5 * 16));

        projh(1, h2, X);               // K overwrites Q (qp extracted)

        float s[F];
#pragma unroll
        for (int kk = 0; kk < F; ++kk) s[kk] = 0.f;
#pragma unroll
        for (int j5 = 0; j5 < 5; ++j5) {
            float qf[8];
#pragma unroll
            for (int j = 0; j < 8; ++j) qf[j] = bf2f((unsigned short)qp[j5][j]);
#pragma unroll
            for (int kk = 0; kk < F; ++kk) {
                short8 k8 = *(const short8*)(X + hswz(kk, cb + j5 * 16));
#pragma unroll
                for (int j = 0; j < 8; ++j) s[kk] += qf[j] * bf2f((unsigned short)k8[j]);
            }
        }
        float m = -1e30f;
#pragma unroll
        for (int kk = 0; kk < F; ++kk) {
            s[kk] = (kk <= lr) ? s[kk] * scale : -1e30f;
            m = fmaxf(m, s[kk]);
        }
        float sum = 0.f;
#pragma unroll
        for (int kk = 0; kk < F; ++kk) { s[kk] = __expf(s[kk] - m); sum += s[kk]; }
        const float inv = 1.f / sum;
#pragma unroll
        for (int kk = 0; kk < F; ++kk) s[kk] *= inv;

        projh(2, h2, X);               // V overwrites K (scores in regs)

        // PV chunked; attn-out overwrites V in place. For chunk j5: all 16
        // row-reads of chunk j5 precede the single row-lr write of chunk j5;
        // later chunks untouched (per-row bijective swizzle).
#pragma unroll
        for (int j5 = 0; j5 < 5; ++j5) {
            float a8[8];
#pragma unroll
            for (int j = 0; j < 8; ++j) a8[j] = 0.f;
#pragma unroll
            for (int kk = 0; kk < F; ++kk) {
                short8 v8 = *(const short8*)(X + hswz(kk, cb + j5 * 16));
#pragma unroll
                for (int j = 0; j < 8; ++j) a8[j] += s[kk] * bf2f((unsigned short)v8[j]);
            }
            short8 t;
#pragma unroll
            for (int j = 0; j < 8; ++j) t[j] = (short)f2bf(a8[j]);
            *(short8*)(X + hswz(lr, cb + j5 * 16)) = t;
        }
    }

    // ---- output projection: out = ao @ Wo.T + bo ----
    // A-frag ks: global dims ks*32+g*8 -> half ks/5 (static), local chunk
    // ks*4+g-20*(ks/5)
    short8 aof[KS];
#pragma unroll
    for (int ks = 0; ks < KS; ++ks) {
        const char* Xh = (ks < 5) ? X0 : X1;
        const int chunk = ks * 4 + g - 20 * (ks / 5);
        aof[ks] = *(const short8*)(Xh + hswz(lr, chunk * 16));
    }

    {
        const char* base = wl + (size_t)(3 * NT) * KS * 1024;
        short8 fa[KS], fb[KS];
#pragma unroll
        for (int ks = 0; ks < KS; ++ks)
            fa[ks] = *(const short8*)(base + (size_t)ks * 1024);
#pragma unroll 1
        for (int np = 0; np < 10; ++np) {
#pragma unroll
            for (int ks = 0; ks < KS; ++ks)
                fb[ks] = *(const short8*)(base + (size_t)((2 * np + 1) * KS + ks) * 1024);
            f32x4 a0 = {0.f, 0.f, 0.f, 0.f};
#pragma unroll
            for (int ks = 0; ks < KS; ++ks)
                a0 = __builtin_amdgcn_mfma_f32_16x16x32_bf16(aof[ks], fa[ks], a0, 0, 0, 0);
            if (np < 9) {
#pragma unroll
                for (int ks = 0; ks < KS; ++ks)
                    fa[ks] = *(const short8*)(base + (size_t)((2 * np + 2) * KS + ks) * 1024);
            }
            f32x4 a1 = {0.f, 0.f, 0.f, 0.f};
#pragma unroll
            for (int ks = 0; ks < KS; ++ks)
                a1 = __builtin_amdgcn_mfma_f32_16x16x32_bf16(aof[ks], fb[ks], a1, 0, 0, 0);

            const int c0 = 2 * np * 16 + lr;
            const int c1 = c0 + 16;
            const float bias0 = bo[c0];
            const float bias1 = bo[c1];
            // paired stores cover one full 128B line per output row
#pragma unroll
            for (int r = 0; r < 4; ++r) {
                float* rowp = out + ((size_t)(bi * F + g * 4 + r) * DDIM + di) * CDIM;
                rowp[c0] = a0[r] + bias0;
                rowp[c1] = a1[r] + bias1;
            }
        }
    }
}

extern "C" void kernel_launch(void* const* d_in, const int* in_sizes, int n_in,
                              void* d_out, int out_size, void* d_ws, size_t ws_size,
                              hipStream_t stream) {
    const float* hs = (const float*)d_in[0];
    const float* Wq = (const float*)d_in[1];
    const float* Wk = (const float*)d_in[2];
    const float* Wv = (const float*)d_in[3];
    const float* Wo = (const float*)d_in[4];
    const float* bo = (const float*)d_in[5];
    float* out = (float*)d_out;
    char* wpk = (char*)d_ws;   // 4*200*1024 = 819200 B of packed bf16 weights

    pack_weights_kernel<<<dim3((4 * NT * KS * 64 + 255) / 256), dim3(256), 0, stream>>>(
        Wq, Wk, Wv, Wo, wpk);

    const int lds = WPB * 2 * HBUF;   // 40960 B -> 4 blocks/CU (16 waves/CU)
    (void)hipFuncSetAttribute((const void*)temporal_attn_kernel,
                              hipFuncAttributeMaxDynamicSharedMemorySize, lds);
    temporal_attn_kernel<<<dim3(NSEQ / WPB), dim3(THREADS), lds, stream>>>(
        hs, wpk, bo, out);
}